// Round 10
// baseline (148.208 us; speedup 1.0000x reference)
//
#include <hip/hip_runtime.h>

// Problem constants (B,C,T,H,HI) = (256, 64, 512, 8, 3)
constexpr int Tn = 512;
constexpr int Cn = 64;

typedef __attribute__((ext_vector_type(8))) short short8;   // bf16x8 MFMA frag
typedef __attribute__((ext_vector_type(4))) float f32x4;
typedef __attribute__((ext_vector_type(4))) int   i32x4;

__device__ __forceinline__ unsigned cvt_pk_bf16(float lo, float hi) {
    unsigned r;
    asm("v_cvt_pk_bf16_f32 %0, %1, %2" : "=v"(r) : "v"(lo), "v"(hi));
    return r;
}
// xor-16 lane exchange (grp0<->grp1, grp2<->grp3) on the LDS crossbar.
__device__ __forceinline__ float swz_xor16(float v) {
    int i = __builtin_bit_cast(int, v);
    i = __builtin_amdgcn_ds_swizzle(i, 0x401F);
    return __builtin_bit_cast(float, i);
}

// Bidirectional per-channel RNN scan via MFMA, T chunked 4x128 with 32-step
// zero-state warmup (contraction makes truncated history error < 1e-4).
// One wave = (dir, channel, batch-group-of-16, chunk). Step:
//   h' = relu( W_aug . [h; x; m; d; 1] )  -- one mfma_f32_16x16x32_bf16.
// Slot scheme (HW-verified in r6): A/B use elems i=0..3 per lane-group g as 16
// abstract k-slots; g0 = W[:,0:4] x h[0:4] (G0's own D), g1 = W[:,4:8] x h[4:8]
// (G1's own D), g2 = (V0,V1,V2,c) x (x,m,d,1), g3 unused (A cols zero).
// acc layout = [b][c][t] (same as x); each lane stores 16 t's as 4 float4s.
__global__ __launch_bounds__(256, 4) void mrnn_scan(
    const float* __restrict__ x, const float* __restrict__ m, const float* __restrict__ d,
    const float* __restrict__ Wf, const float* __restrict__ Vf, const float* __restrict__ cf,
    const float* __restrict__ Wb, const float* __restrict__ Vb, const float* __restrict__ cbk,
    const float* __restrict__ Uu, float* __restrict__ accF, float* __restrict__ accB)
{
    const int w    = blockIdx.x * 4 + (threadIdx.x >> 6);  // 0..8191
    const int lane = threadIdx.x & 63;
    const int col  = lane & 15;        // batch within group; also A row
    const int grp  = lane >> 4;
    const int k    = w & 3;            // T-chunk
    const int bg   = (w >> 2) & 15;
    const int c    = (w >> 6) & 63;
    const int dir  = w >> 12;
    const int b    = bg * 16 + col;

    const float* W  = dir ? Wb  : Wf;
    const float* V  = dir ? Vb  : Vf;
    const float* cc = dir ? cbk : cf;

    // ---- A fragment (constant over steps; verified r6) ----
    float a0 = 0.f, a1 = 0.f, a2 = 0.f, a3 = 0.f;
    {
        const int row = col;
        if (row < 8) {
            if (grp == 0) {
                const float* Wc = W + c*64 + row*8;
                a0 = Wc[0]; a1 = Wc[1]; a2 = Wc[2]; a3 = Wc[3];
            } else if (grp == 1) {
                const float* Wc = W + c*64 + row*8;
                a0 = Wc[4]; a1 = Wc[5]; a2 = Wc[6]; a3 = Wc[7];
            } else if (grp == 2) {
                a0 = V[c*24 + row*3 + 0];
                a1 = V[c*24 + row*3 + 1];
                a2 = V[c*24 + row*3 + 2];
                a3 = cc[c*8 + row];
            }
        }
    }
    i32x4 ai = { (int)cvt_pk_bf16(a0, a1), (int)cvt_pk_bf16(a2, a3), 0, 0 };
    const short8 Afrag = __builtin_bit_cast(short8, ai);

    // ---- U entries for this lane's hidden rows ----
    float U0 = 0.f, U1 = 0.f, U2 = 0.f, U3 = 0.f;
    if (grp < 2) {
        const float* Uc = Uu + c*16 + dir*8 + grp*4;
        U0 = Uc[0]; U1 = Uc[1]; U2 = Uc[2]; U3 = Uc[3];
    }
    const bool isG2 = (grp == 2);

    const f32x4 z4 = {0.f, 0.f, 0.f, 0.f};
    f32x4 hS = z4;    // h state: G0 rows 0-3, G1 rows 4-7 (G2/G3 = 0)

    // One recurrence step; returns the xor16-reduced U·h (valid on lanes 0-31).
    auto step = [&](float xv, float mv, float dv) -> float {
        float s0 = isG2 ? xv   : hS[0];
        float s1 = isG2 ? mv   : hS[1];
        float s2 = isG2 ? dv   : hS[2];
        float s3 = isG2 ? 1.0f : hS[3];
        i32x4 bi = { (int)cvt_pk_bf16(s0, s1), (int)cvt_pk_bf16(s2, s3), 0, 0 };
        short8 Bfrag = __builtin_bit_cast(short8, bi);
        f32x4 Dn = __builtin_amdgcn_mfma_f32_16x16x32_bf16(Afrag, Bfrag, z4, 0, 0, 0);
        Dn[0] = fmaxf(Dn[0], 0.f);
        Dn[1] = fmaxf(Dn[1], 0.f);
        Dn[2] = fmaxf(Dn[2], 0.f);
        Dn[3] = fmaxf(Dn[3], 0.f);
        hS = Dn;
        float p = U0*Dn[0] + U1*Dn[1] + U2*Dn[2] + U3*Dn[3];
        return p + swz_xor16(p);
    };

    const size_t rbase = ((size_t)b * Cn + c) * Tn;
    const float*  xp  = x + rbase;
    const float*  mp  = m + rbase;
    const float*  dp  = d + rbase;
    const float4* x4p = (const float4*)xp;
    const float4* m4p = (const float4*)mp;
    const float4* d4p = (const float4*)dp;
    float* ap = (dir ? accB : accF) + rbase;

    float cx, cm, cd;
    float4 st0, st1, st2, st3;

    if (dir == 0) {
        // forward: step t uses u = max(t-1,0); chunk k outputs t in [128k,128k+128)
        const int nw = (k == 0) ? 0 : 2;             // 2 warmup 16-groups = 32 steps
        const int gstart = 128*k - 16*nw;
        const int u0 = (k == 0) ? 0 : (128*k - 33);
        cx = xp[u0]; cm = mp[u0]; cd = dp[u0];
        #pragma unroll 1
        for (int i = 0; i < 8 + 2; ++i) {
            if (i >= 8 + nw) break;
            const int gb = gstart + 16*i;
            const int q0 = gb >> 2;
            const float4 X0 = x4p[q0],   X1 = x4p[q0+1], X2 = x4p[q0+2], X3 = x4p[q0+3];
            const float4 M0 = m4p[q0],   M1 = m4p[q0+1], M2 = m4p[q0+2], M3 = m4p[q0+3];
            const float4 D0 = d4p[q0],   D1 = d4p[q0+1], D2 = d4p[q0+2], D3 = d4p[q0+3];
            st0.x = step(cx,   cm,   cd);     // t=gb,    u=gb-1 (carry)
            st0.y = step(X0.x, M0.x, D0.x);   // t=gb+1,  u=gb
            st0.z = step(X0.y, M0.y, D0.y);
            st0.w = step(X0.z, M0.z, D0.z);
            st1.x = step(X0.w, M0.w, D0.w);
            st1.y = step(X1.x, M1.x, D1.x);
            st1.z = step(X1.y, M1.y, D1.y);
            st1.w = step(X1.z, M1.z, D1.z);
            st2.x = step(X1.w, M1.w, D1.w);
            st2.y = step(X2.x, M2.x, D2.x);
            st2.z = step(X2.y, M2.y, D2.y);
            st2.w = step(X2.z, M2.z, D2.z);
            st3.x = step(X2.w, M2.w, D2.w);
            st3.y = step(X3.x, M3.x, D3.x);
            st3.z = step(X3.y, M3.y, D3.y);
            st3.w = step(X3.z, M3.z, D3.z);   // t=gb+15, u=gb+14
            cx = X3.w; cm = M3.w; cd = D3.w;  // u=gb+15 for next group
            if (i >= nw && lane < 16) {
                *(float4*)(ap + gb)      = st0;
                *(float4*)(ap + gb + 4)  = st1;
                *(float4*)(ap + gb + 8)  = st2;
                *(float4*)(ap + gb + 12) = st3;
            }
        }
    } else {
        // backward: pos descends; u = min(pos+1, 511); chunk k outputs pos [128k,128k+128)
        const int nw = (k == 3) ? 0 : 2;
        const int gstart = 128*k + 112 + 16*nw;
        const int u0 = (k == 3) ? 511 : (128*k + 160);
        cx = xp[u0]; cm = mp[u0]; cd = dp[u0];
        #pragma unroll 1
        for (int i = 0; i < 8 + 2; ++i) {
            if (i >= 8 + nw) break;
            const int gb = gstart - 16*i;
            const int q0 = gb >> 2;
            const float4 X0 = x4p[q0],   X1 = x4p[q0+1], X2 = x4p[q0+2], X3 = x4p[q0+3];
            const float4 M0 = m4p[q0],   M1 = m4p[q0+1], M2 = m4p[q0+2], M3 = m4p[q0+3];
            const float4 D0 = d4p[q0],   D1 = d4p[q0+1], D2 = d4p[q0+2], D3 = d4p[q0+3];
            st3.w = step(cx,   cm,   cd);     // pos gb+15, u=gb+16 (carry)
            st3.z = step(X3.w, M3.w, D3.w);   // pos gb+14, u=gb+15
            st3.y = step(X3.z, M3.z, D3.z);
            st3.x = step(X3.y, M3.y, D3.y);
            st2.w = step(X3.x, M3.x, D3.x);
            st2.z = step(X2.w, M2.w, D2.w);
            st2.y = step(X2.z, M2.z, D2.z);
            st2.x = step(X2.y, M2.y, D2.y);
            st1.w = step(X2.x, M2.x, D2.x);
            st1.z = step(X1.w, M1.w, D1.w);
            st1.y = step(X1.z, M1.z, D1.z);
            st1.x = step(X1.y, M1.y, D1.y);
            st0.w = step(X1.x, M1.x, D1.x);
            st0.z = step(X0.w, M0.w, D0.w);
            st0.y = step(X0.z, M0.z, D0.z);
            st0.x = step(X0.y, M0.y, D0.y);   // pos gb, u=gb+1
            cx = X0.x; cm = M0.x; cd = D0.x;  // u=gb for next group
            if (i >= nw && lane < 16) {
                *(float4*)(ap + gb)      = st0;
                *(float4*)(ap + gb + 4)  = st1;
                *(float4*)(ap + gb + 8)  = st2;
                *(float4*)(ap + gb + 12) = st3;
            }
        }
    }
}

// Combine + cross-channel bottleneck MLP. One thread per (b,t).
// acc layout now [b][c][t] == x layout, so ALL loads (acc, x, m) and stores
// are instruction-coalesced (lanes = consecutive t).
__global__ __launch_bounds__(256, 2) void mrnn_mix(
    const float* __restrict__ x, const float* __restrict__ m,
    const float* __restrict__ accF, const float* __restrict__ accB,
    const float* __restrict__ c0, const float* __restrict__ V1w,
    const float* __restrict__ V2w, const float* __restrict__ Uw,
    const float* __restrict__ Ub, const float* __restrict__ Ww,
    const float* __restrict__ Wbias, float* __restrict__ out)
{
    const int bt = blockIdx.x * 256 + threadIdx.x;   // 0..131071
    const int b = bt >> 9;
    const int t = bt & 511;
    const size_t xb = (size_t)b * (Cn * Tn) + t;

    float h0 = Ub[0], h1 = Ub[1], h2 = Ub[2];
    #pragma unroll 16
    for (int c = 0; c < Cn; ++c) {
        const size_t off = xb + (size_t)c * Tn;
        const float xe = fmaxf(accF[off] + accB[off] + c0[c], 0.f);
        const float mv = m[off];
        const float xv = x[off];
        const float u0 = (c == 0) ? 0.f : Uw[0*Cn + c];
        const float u1 = (c == 1) ? 0.f : Uw[1*Cn + c];
        const float u2 = (c == 2) ? 0.f : Uw[2*Cn + c];
        h0 += V1w[0*Cn + c]*xe + V2w[0*Cn + c]*mv + u0*xv;
        h1 += V1w[1*Cn + c]*xe + V2w[1*Cn + c]*mv + u1*xv;
        h2 += V1w[2*Cn + c]*xe + V2w[2*Cn + c]*mv + u2*xv;
    }
    h0 = fmaxf(h0, 0.f); h1 = fmaxf(h1, 0.f); h2 = fmaxf(h2, 0.f);

    float* opt = out + xb;
    #pragma unroll
    for (int c = 0; c < Cn; ++c) {
        opt[(size_t)c * Tn] = Wbias[c] + Ww[c*3 + 0]*h0 + Ww[c*3 + 1]*h1 + Ww[c*3 + 2]*h2;
    }
}

extern "C" void kernel_launch(void* const* d_in, const int* in_sizes, int n_in,
                              void* d_out, int out_size, void* d_ws, size_t ws_size,
                              hipStream_t stream)
{
    const float* x   = (const float*)d_in[0];
    const float* m   = (const float*)d_in[1];
    const float* d   = (const float*)d_in[2];
    const float* Wf  = (const float*)d_in[3];
    const float* Vf  = (const float*)d_in[4];
    const float* cf  = (const float*)d_in[5];
    const float* Wb  = (const float*)d_in[6];
    const float* Vb  = (const float*)d_in[7];
    const float* cb  = (const float*)d_in[8];
    const float* U   = (const float*)d_in[9];
    const float* c0  = (const float*)d_in[10];
    const float* V1w = (const float*)d_in[11];
    const float* V2w = (const float*)d_in[12];
    const float* Uw  = (const float*)d_in[13];
    const float* Ub  = (const float*)d_in[14];
    const float* Ww  = (const float*)d_in[15];
    const float* Wb_ = (const float*)d_in[16];
    float* out = (float*)d_out;

    // Workspace: accF and accB planes, each B*C*T floats (33.5 MB), [b][c][t].
    float* accF = (float*)d_ws;
    float* accB = accF + (size_t)Tn * 16384;

    // 2 dir x 64 c x 16 bg x 4 chunks = 8192 waves = 2048 blocks
    mrnn_scan<<<2048, 256, 0, stream>>>(x, m, d, Wf, Vf, cf, Wb, Vb, cb, U, accF, accB);
    // one thread per (b,t) = 131072 threads
    mrnn_mix<<<512, 256, 0, stream>>>(x, m, accF, accB, c0, V1w, V2w, Uw, Ub, Ww, Wb_, out);
}